// Round 1
// baseline (52.770 us; speedup 1.0000x reference)
//
#include <hip/hip_runtime.h>
#include <stdint.h>

// Problem constants
#define Q_ROWS 32768
#define C_REAL 1000
#define C_PAD  1024
#define D_DIM  128
#define KTOT   160          // 128 features + a2 + 1 + 30 zero pad (5 MFMA k-steps of 32)
#define KP     168          // padded LDS/ws row stride in bf16 elems (336B -> bank-friendly)
#define BM     128
#define BN     128
#define NCHUNK (C_PAD / BN) // 8
#define CHUNK_BYTES (BN * KP * 2)   // 43008
#define VP_BYTES (C_PAD * KP * 2)   // 344064

typedef __attribute__((ext_vector_type(8))) short short8;   // 8 bf16 = 4 VGPR
typedef __attribute__((ext_vector_type(4))) float f32x4;    // MFMA 16x16 accumulator

__device__ __forceinline__ uint16_t f2bf(float x) {
    union { float f; uint32_t u; } v; v.f = x;
    uint32_t r = v.u + 0x7FFFu + ((v.u >> 16) & 1u);  // RTNE, no NaN inputs here
    return (uint16_t)(r >> 16);
}

typedef const __attribute__((address_space(1))) uint32_t gu32;
typedef __attribute__((address_space(3))) uint32_t lu32;

__device__ __forceinline__ void gl_lds16(const void* g, void* l) {
    __builtin_amdgcn_global_load_lds((gu32*)g, (lu32*)l, 16, 0, 0);
}

// ---------------------------------------------------------------------------
// Prep: build augmented prototype matrix Vp[1024][168] bf16 in workspace.
//   real row j<1000 : [-2*p_j (128) | 1.0 | b2_j | zeros...]
//   pad  row j>=1000: [ 0 ... | 0 | -1e30 | zeros...]  -> u.v = -1e30 -> g()=0
// ---------------------------------------------------------------------------
__global__ void prep_v(const float* __restrict__ P, uint16_t* __restrict__ vp) {
    const int lane = threadIdx.x & 63;
    const int wid  = threadIdx.x >> 6;
    const int j = blockIdx.x * 4 + wid;
    if (j >= C_PAD) return;
    const bool real = (j < C_REAL);

    float2 pv = make_float2(0.f, 0.f);
    if (real) pv = *(const float2*)(P + (size_t)j * D_DIM + lane * 2);
    float sq = pv.x * pv.x + pv.y * pv.y;
    #pragma unroll
    for (int m = 1; m < 64; m <<= 1) sq += __shfl_xor(sq, m);

    uint16_t* row = vp + (size_t)j * KP;
    ushort2 w;
    w.x = f2bf(-2.f * pv.x);
    w.y = f2bf(-2.f * pv.y);
    *(ushort2*)(row + lane * 2) = w;

    if (lane < 5) {
        uint4 z4 = make_uint4(0u, 0u, 0u, 0u);
        if (lane == 0) {
            uint32_t s128 = real ? 0x3F80u : 0u;              // v[128] = 1.0 (mults a2)
            uint32_t s129 = real ? (uint32_t)f2bf(sq)         // v[129] = b2  (mults 1)
                                 : (uint32_t)f2bf(-1e30f);    // pad sentinel
            z4.x = s128 | (s129 << 16);
        }
        *(uint4*)((char*)row + 256 + lane * 16) = z4;         // slots 128..167
    }
}

// ---------------------------------------------------------------------------
// Main: per block, stage 128 feature rows (f32->bf16 + a2 + 1) into LDS once,
// then loop 8 column chunks: global_load_lds Vp chunk, MFMA 16x16x32 bf16,
// apply g() elementwise, accumulate. Deterministic per-block partial sums.
// ---------------------------------------------------------------------------
__global__ __launch_bounds__(256) void pair_loss_main(
        const float* __restrict__ F,
        const uint16_t* __restrict__ vp,
        float* __restrict__ partials) {
    __shared__ uint16_t As[BM * KP];
    __shared__ uint16_t Bs[BN * KP];
    __shared__ float red[4];

    const int tid  = threadIdx.x;
    const int lane = tid & 63;
    const int wid  = tid >> 6;
    const int row0 = blockIdx.x * BM;

    // ---- Stage A tile: 128 rows x 128 f32 -> bf16, augmented [a2, 1, 0..] ----
    #pragma unroll
    for (int g = 0; g < 16; ++g) {
        int idx = g * 256 + tid;
        int r   = idx >> 5;        // 0..127 (one row per 32 consecutive threads)
        int c4  = idx & 31;        // float4 index
        float4 v = *(const float4*)(F + (size_t)(row0 + r) * D_DIM + c4 * 4);
        float sq = v.x * v.x + v.y * v.y + v.z * v.z + v.w * v.w;
        #pragma unroll
        for (int m = 1; m < 32; m <<= 1) sq += __shfl_xor(sq, m);

        ushort4 w4;
        w4.x = f2bf(v.x); w4.y = f2bf(v.y); w4.z = f2bf(v.z); w4.w = f2bf(v.w);
        *(ushort4*)((char*)As + r * (KP * 2) + c4 * 8) = w4;

        int gl = tid & 31;
        if (gl < 4) {
            uint4 z4 = make_uint4(0u, 0u, 0u, 0u);
            if (gl == 0) z4.x = (uint32_t)f2bf(sq) | (0x3F80u << 16);  // [a2, 1.0]
            *(uint4*)((char*)As + r * (KP * 2) + 256 + gl * 16) = z4;  // slots 128..159
        }
    }

    const int wr = wid >> 1;   // wave tile: 64x64 of the 128x128 chunk
    const int wc = wid & 1;
    float gsum = 0.f;

    for (int c = 0; c < NCHUNK; ++c) {
        // ---- Stage B chunk (contiguous 43008B) via async global->LDS ----
        const char* src = (const char*)vp + (size_t)c * CHUNK_BYTES;
        for (int jj = wid; jj < CHUNK_BYTES / 1024; jj += 4) {
            gl_lds16(src + jj * 1024 + lane * 16, (char*)Bs + jj * 1024);
        }
        __syncthreads();   // drains vmcnt (global_load_lds) + lgkmcnt (A ds_writes)

        f32x4 acc[4][4];
        #pragma unroll
        for (int m = 0; m < 4; ++m)
            #pragma unroll
            for (int n = 0; n < 4; ++n)
                acc[m][n] = (f32x4){0.f, 0.f, 0.f, 0.f};

        #pragma unroll
        for (int kk = 0; kk < 5; ++kk) {
            const int kbyte = kk * 64 + ((lane >> 4) & 3) * 16;
            short8 a[4], b[4];
            #pragma unroll
            for (int m = 0; m < 4; ++m) {
                int r = wr * 64 + m * 16 + (lane & 15);
                a[m] = *(const short8*)((const char*)As + r * (KP * 2) + kbyte);
            }
            #pragma unroll
            for (int n = 0; n < 4; ++n) {
                int r = wc * 64 + n * 16 + (lane & 15);
                b[n] = *(const short8*)((const char*)Bs + r * (KP * 2) + kbyte);
            }
            #pragma unroll
            for (int m = 0; m < 4; ++m)
                #pragma unroll
                for (int n = 0; n < 4; ++n)
                    acc[m][n] = __builtin_amdgcn_mfma_f32_16x16x32_bf16(
                        a[m], b[n], acc[m][n], 0, 0, 0);
        }

        // ---- Elementwise g(z) + accumulate. z = d2 (B-TAO = 0). ----
        #pragma unroll
        for (int m = 0; m < 4; ++m) {
            #pragma unroll
            for (int n = 0; n < 4; ++n) {
                #pragma unroll
                for (int e = 0; e < 4; ++e) {
                    float z = acc[m][n][e];
                    float gv = z;
                    if (__builtin_expect(z < 10.f, 0))
                        gv = log1pf(expf(0.1f * z)) * 10.f;  // softplus/beta; pad cols -> 0
                    gsum += gv;
                }
            }
        }
        __syncthreads();   // protect Bs before next chunk's staging
    }

    // ---- deterministic block reduction ----
    #pragma unroll
    for (int m = 1; m < 64; m <<= 1) gsum += __shfl_xor(gsum, m);
    if (lane == 0) red[wid] = gsum;
    __syncthreads();
    if (tid == 0) partials[blockIdx.x] = (red[0] + red[1]) + (red[2] + red[3]);
}

// ---------------------------------------------------------------------------
// Final: deterministic reduction of 256 block partials -> mean
// ---------------------------------------------------------------------------
__global__ void final_reduce(const float* __restrict__ partials, float* __restrict__ out) {
    __shared__ float red[4];
    const int tid = threadIdx.x;
    const int lane = tid & 63;
    const int wid = tid >> 6;
    float v = partials[tid];
    #pragma unroll
    for (int m = 1; m < 64; m <<= 1) v += __shfl_xor(v, m);
    if (lane == 0) red[wid] = v;
    __syncthreads();
    if (tid == 0)
        out[0] = ((red[0] + red[1]) + (red[2] + red[3])) *
                 (1.0f / ((float)Q_ROWS * (float)C_REAL));
}

extern "C" void kernel_launch(void* const* d_in, const int* in_sizes, int n_in,
                              void* d_out, int out_size, void* d_ws, size_t ws_size,
                              hipStream_t stream) {
    const float* F = (const float*)d_in[0];      // features [32768,128] f32
    // d_in[1] = labels (int64) — mathematically unused in the reference
    const float* P = (const float*)d_in[2];      // prototypes [1000,128] f32
    float* out = (float*)d_out;

    uint16_t* vp = (uint16_t*)d_ws;                          // VP_BYTES
    float* partials = (float*)((char*)d_ws + VP_BYTES);      // 256 floats

    prep_v<<<C_PAD / 4, 256, 0, stream>>>(P, vp);
    pair_loss_main<<<Q_ROWS / BM, 256, 0, stream>>>(F, vp, partials);
    final_reduce<<<1, 256, 0, stream>>>(partials, out);
}